// Round 3
// baseline (764.503 us; speedup 1.0000x reference)
//
#include <hip/hip_runtime.h>

typedef __attribute__((ext_vector_type(4))) float f32x4_t;
typedef __attribute__((ext_vector_type(8))) short bf16x8_t;

#define NROWS 16384
#define NCODES 4096
#define DIM 512
#define GROUPS 8
#define SP 40            // padded LDS row stride in bf16 elems (80 B, 16B-aligned, 2-way banks)
#define LSTR 65          // logits LDS stride (f32)
#define MARGIN 1.5e-4f   // >= 4x worst-case hi/lo-split GEMM error bound

// workspace byte offsets (total ~3.70 MB, no overlaps)
#define WS_INV_NZ 0          // 16384 f32  -> ends   65536
#define WS_INV_NC 65536      //  4096 f32  -> ends   81920
#define WS_COUNTS 81920      //  4096 u32  -> ends   98304
#define WS_FLAGS  98304      // [0]=mask-layout, [1]=pair_cnt, [2]=full_cnt
#define WS_TOP3   131072     // 16384*8*(3f32+3i32) -> ends 3276800
#define WS_IDX    3276800    // 16384 i32  -> ends 3342336
#define WS_PAIRS  3342336    // 16384 int4 -> ends 3604480
#define WS_FULL   3604480    // 16384 i32  -> ends 3670016
#define WS_CPART  3670016    //  4096 f64  -> ends 3702784

// output element offsets (flat f32)
#define OUT_ZQ      0
#define OUT_ZQST    8388608
#define OUT_IDX     16777216
#define OUT_VQ      16793600
#define OUT_COMMIT  16793601
#define OUT_PERP    16793602

__device__ __forceinline__ unsigned short f2bf(float x) {
  unsigned u = __builtin_bit_cast(unsigned, x);
  unsigned r = (u + 0x7FFFu + ((u >> 16) & 1u)) >> 16;  // RNE
  return (unsigned short)r;
}
__device__ __forceinline__ float bf2f(unsigned short b) {
  return __builtin_bit_cast(float, ((unsigned)b) << 16);
}
__device__ __forceinline__ unsigned hz(unsigned x) {
  return (x - 0x01010101u) & ~x & 0x80808080u;  // any zero byte
}

// ---------------- mask layout probe ----------------
__global__ void mask_probe_kernel(const uint4* __restrict__ m, unsigned* __restrict__ flag) {
  unsigned f = 0;
  for (int i = threadIdx.x; i < 1024; i += 256) {  // first 16384 bytes
    uint4 v = m[i];
    f |= hz(v.x) | hz(v.y) | hz(v.z) | hz(v.w);
  }
  if (f) atomicOr(flag, 1u);  // zero byte found -> int32 layout
}

// ---------------- row norms (one wave per row) ----------------
__global__ void norms_kernel(const float* __restrict__ z, const float* __restrict__ cb,
                             float* __restrict__ inv_nz, float* __restrict__ inv_nc) {
  const int wv = threadIdx.x >> 6, lane = threadIdx.x & 63;
  const int row = blockIdx.x * 4 + wv;
  if (row >= NROWS + NCODES) return;
  const float* src = (row < NROWS) ? (z + (size_t)row * DIM) : (cb + (size_t)(row - NROWS) * DIM);
  f32x4_t a = *(const f32x4_t*)(src + lane * 8);
  f32x4_t b = *(const f32x4_t*)(src + lane * 8 + 4);
  double s = 0.0;
#pragma unroll
  for (int e = 0; e < 4; ++e) s += (double)a[e] * a[e] + (double)b[e] * b[e];
#pragma unroll
  for (int off = 32; off; off >>= 1) s += __shfl_down(s, off);
  if (lane == 0) {
    float r = (float)(1.0 / fmax(sqrt(s), 1e-8));
    if (row < NROWS) inv_nz[row] = r; else inv_nc[row - NROWS] = r;
  }
}

// ---------------- hi/lo split GEMM + per-row top-3 ----------------
// grid: 128 row-blocks x 8 col-groups; block = 256 thr (4 waves, 2x2), tile 128x128, BK=32
__global__ __launch_bounds__(256, 2) void gemm_top3_kernel(
    const float* __restrict__ z, const float* __restrict__ cb,
    const float* __restrict__ inv_nz, const float* __restrict__ inv_nc,
    float* __restrict__ top3) {
  __shared__ unsigned short smem_u[20480];  // 40 KB
  unsigned short* sAh = smem_u;
  unsigned short* sAl = smem_u + 5120;
  unsigned short* sBh = smem_u + 10240;
  unsigned short* sBl = smem_u + 15360;
  float* slog = (float*)smem_u;  // [128][65] union (33280 B)

  const int tid = threadIdx.x;
  const int rb = blockIdx.x >> 3;
  const int cg = blockIdx.x & 7;
  const int wave = tid >> 6, lane = tid & 63;
  const int wr = wave >> 1, wc = wave & 1;
  const int kg = lane >> 4, lr = lane & 15;
  const int srow = tid >> 3;          // 0..31
  const int scol = (tid & 7) << 2;    // 0,4,...,28

  float nza[4];
#pragma unroll
  for (int q = 0; q < 4; ++q) nza[q] = inv_nz[rb * 128 + q * 32 + srow];

  float v1 = -3e38f, v2 = -3e38f, v3 = -3e38f;
  int i1 = 0, i2 = 0, i3 = 0;

  for (int ct = 0; ct < 4; ++ct) {
    const int code0 = cg * 512 + ct * 128;
    float ncb[4];
#pragma unroll
    for (int q = 0; q < 4; ++q) ncb[q] = inv_nc[code0 + q * 32 + srow];

    f32x4_t acc[4][4];
#pragma unroll
    for (int m = 0; m < 4; ++m)
#pragma unroll
      for (int n = 0; n < 4; ++n) acc[m][n] = (f32x4_t){0.f, 0.f, 0.f, 0.f};

    f32x4_t ra[4], rbv[4];

    auto stage_load = [&](int t) {
      const int kc = t * 32 + scol;
#pragma unroll
      for (int q = 0; q < 4; ++q) {
        ra[q]  = *(const f32x4_t*)(z  + (size_t)(rb * 128 + q * 32 + srow) * DIM + kc);
        rbv[q] = *(const f32x4_t*)(cb + (size_t)(code0   + q * 32 + srow) * DIM + kc);
      }
    };
    auto stage_write = [&]() {
#pragma unroll
      for (int q = 0; q < 4; ++q) {
        const int row = q * 32 + srow;
        ushort4 hv, lv, hv2, lv2;
#pragma unroll
        for (int e = 0; e < 4; ++e) {
          float x = ra[q][e] * nza[q];
          unsigned short h = f2bf(x);
          (&hv.x)[e] = h;
          (&lv.x)[e] = f2bf(x - bf2f(h));
          float y = rbv[q][e] * ncb[q];
          unsigned short h2 = f2bf(y);
          (&hv2.x)[e] = h2;
          (&lv2.x)[e] = f2bf(y - bf2f(h2));
        }
        *(ushort4*)(sAh + row * SP + scol) = hv;
        *(ushort4*)(sAl + row * SP + scol) = lv;
        *(ushort4*)(sBh + row * SP + scol) = hv2;
        *(ushort4*)(sBl + row * SP + scol) = lv2;
      }
    };

    stage_load(0);
    stage_write();
    __syncthreads();

    for (int t = 0; t < 16; ++t) {
      if (t < 15) stage_load(t + 1);  // issue-early: HBM latency hides under MFMA
      bf16x8_t ah[4], al[4], bh[4], bl[4];
#pragma unroll
      for (int m = 0; m < 4; ++m) {
        const int o = (wr * 64 + m * 16 + lr) * SP + kg * 8;
        ah[m] = *(const bf16x8_t*)(sAh + o);
        al[m] = *(const bf16x8_t*)(sAl + o);
      }
#pragma unroll
      for (int n = 0; n < 4; ++n) {
        const int o = (wc * 64 + n * 16 + lr) * SP + kg * 8;
        bh[n] = *(const bf16x8_t*)(sBh + o);
        bl[n] = *(const bf16x8_t*)(sBl + o);
      }
#pragma unroll
      for (int m = 0; m < 4; ++m)
#pragma unroll
        for (int n = 0; n < 4; ++n) {
          acc[m][n] = __builtin_amdgcn_mfma_f32_16x16x32_bf16(ah[m], bh[n], acc[m][n], 0, 0, 0);
          acc[m][n] = __builtin_amdgcn_mfma_f32_16x16x32_bf16(ah[m], bl[n], acc[m][n], 0, 0, 0);
          acc[m][n] = __builtin_amdgcn_mfma_f32_16x16x32_bf16(al[m], bh[n], acc[m][n], 0, 0, 0);
        }
      __syncthreads();
      if (t < 15) stage_write();
      __syncthreads();
    }

    // epilogue: 64-col halves through LDS, per-row top-3 scan
#pragma unroll
    for (int ph = 0; ph < 2; ++ph) {
      if (wc == ph) {
#pragma unroll
        for (int m = 0; m < 4; ++m)
#pragma unroll
          for (int n = 0; n < 4; ++n)
#pragma unroll
            for (int j = 0; j < 4; ++j)
              slog[(wr * 64 + m * 16 + kg * 4 + j) * LSTR + n * 16 + lr] = acc[m][n][j];
      }
      __syncthreads();
      if (tid < 128) {
        const int gbase = code0 + ph * 64;
        for (int c = 0; c < 64; ++c) {
          float v = slog[tid * LSTR + c];
          int gc = gbase + c;
          if (v > v1)      { v3 = v2; i3 = i2; v2 = v1; i2 = i1; v1 = v; i1 = gc; }
          else if (v > v2) { v3 = v2; i3 = i2; v2 = v;  i2 = gc; }
          else if (v > v3) { v3 = v;  i3 = gc; }
        }
      }
      __syncthreads();
    }
  }

  if (tid < 128) {
    float* p = top3 + ((size_t)(rb * 128 + tid) * GROUPS + cg) * 6;
    p[0] = v1; p[1] = v2; p[2] = v3;
    int* pi = (int*)p;
    pi[3] = i1; pi[4] = i2; pi[5] = i3;
  }
}

// ---------------- merge partial top-3, classify rows ----------------
__global__ void resolve_kernel(const float* __restrict__ top3, int* __restrict__ idxf,
                               int4* __restrict__ pairs, unsigned* __restrict__ pcnt,
                               int* __restrict__ full, unsigned* __restrict__ fcnt) {
  const int row = blockIdx.x * 256 + threadIdx.x;
  if (row >= NROWS) return;
  float V1 = -3e38f, V2 = -3e38f, V3 = -3e38f;
  int I1 = 0, I2 = 0, I3 = 0;
  const float* p = top3 + (size_t)row * GROUPS * 6;
  for (int g = 0; g < GROUPS; ++g, p += 6) {
    const int* pi = (const int*)p;
#pragma unroll
    for (int c = 0; c < 3; ++c) {
      float v = p[c]; int i = pi[3 + c];
      if (v > V1)      { V3 = V2; I3 = I2; V2 = V1; I2 = I1; V1 = v; I1 = i; }
      else if (v > V2) { V3 = V2; I3 = I2; V2 = v;  I2 = i; }
      else if (v > V3) { V3 = v;  I3 = i; }
    }
  }
  idxf[row] = I1;
  if (V1 - V2 <= MARGIN) {
    if (V1 - V3 <= MARGIN) {
      unsigned s = atomicAdd(fcnt, 1u);
      if (s < NROWS) full[s] = row;
    } else {
      unsigned s = atomicAdd(pcnt, 1u);
      if (s < NROWS) pairs[s] = make_int4(row, I1, I2, 0);
    }
  }
}

// ---------------- exact f64 rescore of {I1,I2} (one wave per item) ----------------
__global__ void rescore_pairs_kernel(const float* __restrict__ z, const float* __restrict__ cb,
                                     const int4* __restrict__ pairs, const unsigned* __restrict__ pcnt,
                                     int* __restrict__ idxf) {
  const int lane = threadIdx.x & 63;
  const int gw = (blockIdx.x * 256 + threadIdx.x) >> 6;
  const unsigned n = *pcnt;
  for (unsigned it = gw; it < n; it += 512) {
    int4 e = pairs[it];
    const float* zr = z + (size_t)e.x * DIM;
    const float* ca = cb + (size_t)e.y * DIM;
    const float* cc = cb + (size_t)e.z * DIM;
    double da = 0, na = 0, db = 0, nb = 0;
#pragma unroll
    for (int j = 0; j < 8; ++j) {
      int o = lane * 8 + j;
      double zv = zr[o], av = ca[o], bv = cc[o];
      da += zv * av; na += av * av; db += zv * bv; nb += bv * bv;
    }
#pragma unroll
    for (int off = 32; off; off >>= 1) {
      da += __shfl_down(da, off); na += __shfl_down(na, off);
      db += __shfl_down(db, off); nb += __shfl_down(nb, off);
    }
    if (lane == 0) {
      double sa = da / sqrt(na), sb = db / sqrt(nb);
      int w = (sb > sa) ? e.z : ((sa > sb) ? e.y : (e.y < e.z ? e.y : e.z));
      idxf[e.x] = w;
    }
  }
}

// ---------------- exact f64 full-row scan (rare) ----------------
__global__ void rescore_full_kernel(const float* __restrict__ z, const float* __restrict__ cb,
                                    const int* __restrict__ full, const unsigned* __restrict__ fcnt,
                                    int* __restrict__ idxf) {
  __shared__ float zrow[DIM];
  __shared__ double rv[256];
  __shared__ int ri[256];
  const int t = threadIdx.x;
  const unsigned n = *fcnt;
  for (unsigned it = blockIdx.x; it < n; it += gridDim.x) {
    const int row = full[it];
    for (int j = t; j < DIM; j += 256) zrow[j] = z[(size_t)row * DIM + j];
    __syncthreads();
    double bv = -1e300; int bi = 1 << 30;
    for (int k = t; k < NCODES; k += 256) {
      const float* ck = cb + (size_t)k * DIM;
      double d = 0, nn = 0;
      for (int j = 0; j < DIM; ++j) { double c = ck[j]; d += (double)zrow[j] * c; nn += c * c; }
      double s = d / sqrt(nn);
      if (s > bv || (s == bv && k < bi)) { bv = s; bi = k; }
    }
    rv[t] = bv; ri[t] = bi; __syncthreads();
    for (int off = 128; off; off >>= 1) {
      if (t < off) {
        if (rv[t + off] > rv[t] || (rv[t + off] == rv[t] && ri[t + off] < ri[t])) {
          rv[t] = rv[t + off]; ri[t] = ri[t + off];
        }
      }
      __syncthreads();
    }
    if (t == 0) idxf[row] = ri[0];
    __syncthreads();
  }
}

// ---------------- gather + straight-through + partial losses ----------------
__global__ void outputs_kernel(const float* __restrict__ z, const float* __restrict__ cb,
                               const unsigned char* __restrict__ mask8, const int* __restrict__ mask32,
                               const unsigned* __restrict__ flags, const int* __restrict__ idxf,
                               float* __restrict__ out, unsigned* __restrict__ counts,
                               double* __restrict__ cpart) {
  __shared__ double wsum[4];
  const int wv = threadIdx.x >> 6, lane = threadIdx.x & 63;
  const int row = blockIdx.x * 4 + wv;
  int idx = idxf[row];
  idx = (idx < 0) ? 0 : ((idx > NCODES - 1) ? NCODES - 1 : idx);  // defensive clamp
  const int mi = flags[0] ? (mask32[row] != 0) : (mask8[row] != 0);
  const float mf = mi ? 1.0f : 0.0f;
  const float* zr = z + (size_t)row * DIM;
  const float* cr = cb + (size_t)idx * DIM;
  double cs = 0.0;
#pragma unroll
  for (int h = 0; h < 2; ++h) {
    const int j = h * 256 + lane * 4;
    f32x4_t c  = *(const f32x4_t*)(cr + j);
    f32x4_t ze = *(const f32x4_t*)(zr + j);
    f32x4_t zq, zs;
#pragma unroll
    for (int e = 0; e < 4; ++e) {
      float q = c[e] * mf;
      float d = q - ze[e];
      zq[e] = q;
      zs[e] = ze[e] + d;             // matches ref z_e + (z_q - z_e) in f32
      float d2 = d * d;
      cs += (double)d2 * mf;
    }
    *(f32x4_t*)(out + OUT_ZQ   + (size_t)row * DIM + j) = zq;
    *(f32x4_t*)(out + OUT_ZQST + (size_t)row * DIM + j) = zs;
  }
#pragma unroll
  for (int off = 32; off; off >>= 1) cs += __shfl_down(cs, off);
  if (lane == 0) {
    wsum[wv] = cs;
    out[OUT_IDX + row] = (float)idx;
    if (mi) atomicAdd(&counts[idx], 1u);
  }
  __syncthreads();
  if (threadIdx.x == 0) cpart[blockIdx.x] = wsum[0] + wsum[1] + wsum[2] + wsum[3];
}

// ---------------- scalars: vq_loss, commitment, perplexity ----------------
__global__ void finalize_kernel(const double* __restrict__ cpart, const unsigned* __restrict__ counts,
                                float* __restrict__ out) {
  __shared__ double sd[256];
  const int t = threadIdx.x;
  double s = 0;
  for (int i = t; i < 4096; i += 256) s += cpart[i];
  sd[t] = s; __syncthreads();
  for (int off = 128; off; off >>= 1) { if (t < off) sd[t] += sd[t + off]; __syncthreads(); }
  const double commit_sum = sd[0];
  __syncthreads();
  double c = 0;
  for (int i = t; i < 4096; i += 256) c += (double)counts[i];
  sd[t] = c; __syncthreads();
  for (int off = 128; off; off >>= 1) { if (t < off) sd[t] += sd[t + off]; __syncthreads(); }
  const double totc = sd[0];
  __syncthreads();
  const double denom = totc + 1e-5;
  double ent = 0;
  for (int i = t; i < 4096; i += 256) {
    double p = (double)counts[i] / denom;
    ent -= p * log(p + 1e-5);
  }
  sd[t] = ent; __syncthreads();
  for (int off = 128; off; off >>= 1) { if (t < off) sd[t] += sd[t + off]; __syncthreads(); }
  if (t == 0) {
    const double valid = fmax(totc, 1.0);
    const double commitment = commit_sum / valid;
    out[OUT_VQ]     = (float)(0.25 * commitment);
    out[OUT_COMMIT] = (float)commitment;
    out[OUT_PERP]   = (float)exp(sd[0]);
  }
}

extern "C" void kernel_launch(void* const* d_in, const int* in_sizes, int n_in,
                              void* d_out, int out_size, void* d_ws, size_t ws_size,
                              hipStream_t stream) {
  const float* z  = (const float*)d_in[0];
  const void*  mk = d_in[1];
  const float* cb = (const float*)d_in[2];
  float* out = (float*)d_out;
  char* ws = (char*)d_ws;

  float*    inv_nz = (float*)(ws + WS_INV_NZ);
  float*    inv_nc = (float*)(ws + WS_INV_NC);
  unsigned* counts = (unsigned*)(ws + WS_COUNTS);
  unsigned* flags  = (unsigned*)(ws + WS_FLAGS);
  float*    top3   = (float*)(ws + WS_TOP3);
  int*      idxf   = (int*)(ws + WS_IDX);
  int4*     pairs  = (int4*)(ws + WS_PAIRS);
  int*      full   = (int*)(ws + WS_FULL);
  double*   cpart  = (double*)(ws + WS_CPART);

  hipMemsetAsync(ws + WS_COUNTS, 0, (WS_FLAGS - WS_COUNTS) + 64, stream);
  mask_probe_kernel<<<1, 256, 0, stream>>>((const uint4*)mk, flags);
  norms_kernel<<<(NROWS + NCODES) / 4, 256, 0, stream>>>(z, cb, inv_nz, inv_nc);
  gemm_top3_kernel<<<128 * GROUPS, 256, 0, stream>>>(z, cb, inv_nz, inv_nc, top3);
  resolve_kernel<<<NROWS / 256, 256, 0, stream>>>(top3, idxf, pairs, flags + 1, full, flags + 2);
  rescore_pairs_kernel<<<128, 256, 0, stream>>>(z, cb, pairs, flags + 1, idxf);
  rescore_full_kernel<<<32, 256, 0, stream>>>(z, cb, full, flags + 2, idxf);
  outputs_kernel<<<NROWS / 4, 256, 0, stream>>>(z, cb, (const unsigned char*)mk, (const int*)mk,
                                                flags, idxf, out, counts, cpart);
  finalize_kernel<<<1, 256, 0, stream>>>(cpart, counts, out);
}

// Round 4
// 651.721 us; speedup vs baseline: 1.1731x; 1.1731x over previous
//
#include <hip/hip_runtime.h>

typedef __attribute__((ext_vector_type(4))) float f32x4_t;
typedef __attribute__((ext_vector_type(8))) short bf16x8_t;

#define NROWS 16384
#define NCODES 4096
#define DIM 512
#define GROUPS 8
#define SP 40            // v1 padded LDS row stride in bf16 elems
#define LSTR 65          // logits LDS stride (f32)
#define MARGIN 1.5e-4f   // >= 4x worst-case hi/lo-split GEMM error bound

// ---------------- v1 workspace (fallback path, ~3.7 MB) ----------------
#define WS_INV_NZ 0
#define WS_INV_NC 65536
#define WS_COUNTS 81920
#define WS_FLAGS  98304
#define WS_TOP3   131072
#define WS_IDX    3276800
#define WS_PAIRS  3342336
#define WS_FULL   3604480
#define WS_CPART  3670016

// ---------------- v2 workspace (~45.6 MB) ----------------
// A/B stored as per-(tile,ks) 16KB chunks: [hi 8KB | lo 8KB], 16B-unit XOR-swizzled.
#define WS2_A      0u
#define WS2_B      33554432u
#define WS2_INV_NZ 41943040u
#define WS2_INV_NC 42008576u
#define WS2_COUNTS 42024960u
#define WS2_FLAGS  42041344u
#define WS2_TOP3   42045440u
#define WS2_IDX    45191168u
#define WS2_PAIRS  45256704u
#define WS2_FULL   45518848u
#define WS2_CPART  45584384u
#define WS2_TOTAL  45617152u

// output element offsets (flat f32)
#define OUT_ZQ      0
#define OUT_ZQST    8388608
#define OUT_IDX     16777216
#define OUT_VQ      16793600
#define OUT_COMMIT  16793601
#define OUT_PERP    16793602

__device__ __forceinline__ unsigned short f2bf(float x) {
  unsigned u = __builtin_bit_cast(unsigned, x);
  unsigned r = (u + 0x7FFFu + ((u >> 16) & 1u)) >> 16;  // RNE
  return (unsigned short)r;
}
__device__ __forceinline__ float bf2f(unsigned short b) {
  return __builtin_bit_cast(float, ((unsigned)b) << 16);
}
__device__ __forceinline__ unsigned hz(unsigned x) {
  return (x - 0x01010101u) & ~x & 0x80808080u;
}

// ---------------- mask layout probe ----------------
__global__ void mask_probe_kernel(const uint4* __restrict__ m, unsigned* __restrict__ flag) {
  unsigned f = 0;
  for (int i = threadIdx.x; i < 1024; i += 256) {
    uint4 v = m[i];
    f |= hz(v.x) | hz(v.y) | hz(v.z) | hz(v.w);
  }
  if (f) atomicOr(flag, 1u);
}

// ---------------- row norms ----------------
__global__ void norms_kernel(const float* __restrict__ z, const float* __restrict__ cb,
                             float* __restrict__ inv_nz, float* __restrict__ inv_nc) {
  const int wv = threadIdx.x >> 6, lane = threadIdx.x & 63;
  const int row = blockIdx.x * 4 + wv;
  if (row >= NROWS + NCODES) return;
  const float* src = (row < NROWS) ? (z + (size_t)row * DIM) : (cb + (size_t)(row - NROWS) * DIM);
  f32x4_t a = *(const f32x4_t*)(src + lane * 8);
  f32x4_t b = *(const f32x4_t*)(src + lane * 8 + 4);
  double s = 0.0;
#pragma unroll
  for (int e = 0; e < 4; ++e) s += (double)a[e] * a[e] + (double)b[e] * b[e];
#pragma unroll
  for (int off = 32; off; off >>= 1) s += __shfl_down(s, off);
  if (lane == 0) {
    float r = (float)(1.0 / fmax(sqrt(s), 1e-8));
    if (row < NROWS) inv_nz[row] = r; else inv_nc[row - NROWS] = r;
  }
}

// ---------------- v2: precompute normalized bf16 hi/lo operand chunks ----------------
// One thread per 8-col unit. Chunk (tb,ks) = 16KB image the GEMM stages linearly.
__global__ void prep_kernel(const float* __restrict__ src, const float* __restrict__ inv,
                            unsigned char* __restrict__ dst, int nrows) {
  const int t = blockIdx.x * 256 + threadIdx.x;
  const int row = t >> 6, uu = t & 63;
  if (row >= nrows) return;
  const float w = inv[row];
  const float* p = src + (size_t)row * DIM + uu * 8;
  f32x4_t x0 = *(const f32x4_t*)p, x1 = *(const f32x4_t*)(p + 4);
  union { unsigned short s[8]; uint4 v; } H, L;
#pragma unroll
  for (int e = 0; e < 4; ++e) {
    float v0 = x0[e] * w;
    unsigned short h0 = f2bf(v0);
    H.s[e] = h0; L.s[e] = f2bf(v0 - bf2f(h0));
    float v1 = x1[e] * w;
    unsigned short h1 = f2bf(v1);
    H.s[4 + e] = h1; L.s[4 + e] = f2bf(v1 - bf2f(h1));
  }
  const int tb = row >> 7, rr = row & 127, ks = uu >> 2, cu = uu & 3;
  unsigned char* chunk = dst + ((size_t)tb * 16 + ks) * 16384;
  const unsigned off = (unsigned)((rr * 64 + cu * 16) ^ ((rr & 7) << 4));
  *(uint4*)(chunk + off) = H.v;
  *(uint4*)(chunk + 8192 + off) = L.v;
}

// ---------------- v2 GEMM: global_load_lds dbuf + counted vmcnt + top-3 ----------------
__global__ __launch_bounds__(256, 2) void gemm_top3_v2_kernel(
    const unsigned char* __restrict__ Aws, const unsigned char* __restrict__ Bws,
    float* __restrict__ top3) {
  __shared__ unsigned char lds[65536];  // 2 x 32KB: [Ahi 8K|Alo 8K|Bhi 8K|Blo 8K]
  float* slog = (float*)lds;

  const int tid = threadIdx.x;
  const int rb = blockIdx.x >> 3, cg = blockIdx.x & 7;
  const int wave = tid >> 6, lane = tid & 63;
  const int wr = wave >> 1, wc = wave & 1;
  const int kg = lane >> 4, lr = lane & 15;

  float v1 = -3e38f, v2 = -3e38f, v3 = -3e38f;
  int i1 = 0, i2 = 0, i3 = 0;

  const unsigned char* Achunks = Aws + (size_t)rb * 16 * 16384;

  for (int ct = 0; ct < 4; ++ct) {
    const int ctile = cg * 4 + ct;
    const int code0 = ctile * 128;
    const unsigned char* Bchunks = Bws + (size_t)ctile * 16 * 16384;

    f32x4_t acc[4][4];
#pragma unroll
    for (int m = 0; m < 4; ++m)
#pragma unroll
      for (int n = 0; n < 4; ++n) acc[m][n] = (f32x4_t){0.f, 0.f, 0.f, 0.f};

    // prologue: stage ks=0 -> buf0 (per wave: 8 calls x 1KB)
    {
#pragma unroll
      for (int i = 0; i < 8; ++i) {
        const int j = wave * 8 + i;
        const unsigned char* s = (j < 16) ? (Achunks + (size_t)j * 1024 + lane * 16)
                                          : (Bchunks + (size_t)(j - 16) * 1024 + lane * 16);
        __builtin_amdgcn_global_load_lds(
            (const __attribute__((address_space(1))) void*)s,
            (__attribute__((address_space(3))) void*)(lds + j * 1024), 16, 0, 0);
      }
    }

    for (int ks = 0; ks < 16; ++ks) {
      const int cur = ks & 1;
      if (ks < 15) {
        unsigned char* ldsb = lds + (cur ^ 1) * 32768;
        const unsigned char* Ac = Achunks + (size_t)(ks + 1) * 16384;
        const unsigned char* Bc = Bchunks + (size_t)(ks + 1) * 16384;
#pragma unroll
        for (int i = 0; i < 8; ++i) {
          const int j = wave * 8 + i;
          const unsigned char* s = (j < 16) ? (Ac + (size_t)j * 1024 + lane * 16)
                                            : (Bc + (size_t)(j - 16) * 1024 + lane * 16);
          __builtin_amdgcn_global_load_lds(
              (const __attribute__((address_space(1))) void*)s,
              (__attribute__((address_space(3))) void*)(ldsb + j * 1024), 16, 0, 0);
        }
        asm volatile("s_waitcnt vmcnt(8)" ::: "memory");  // drain cur's 8, keep next 8 in flight
      } else {
        asm volatile("s_waitcnt vmcnt(0)" ::: "memory");
      }
      __builtin_amdgcn_s_barrier();

      const unsigned char* base = lds + cur * 32768;
      bf16x8_t ah[4], al[4], bh[4], bl[4];
#pragma unroll
      for (int m = 0; m < 4; ++m) {
        const int r = wr * 64 + m * 16 + lr;
        const unsigned off = (unsigned)((r * 64 + kg * 16) ^ ((r & 7) << 4));
        ah[m] = *(const bf16x8_t*)(base + off);
        al[m] = *(const bf16x8_t*)(base + 8192 + off);
      }
#pragma unroll
      for (int n = 0; n < 4; ++n) {
        const int r = wc * 64 + n * 16 + lr;
        const unsigned off = (unsigned)((r * 64 + kg * 16) ^ ((r & 7) << 4));
        bh[n] = *(const bf16x8_t*)(base + 16384 + off);
        bl[n] = *(const bf16x8_t*)(base + 24576 + off);
      }
#pragma unroll
      for (int m = 0; m < 4; ++m)
#pragma unroll
        for (int n = 0; n < 4; ++n) {
          acc[m][n] = __builtin_amdgcn_mfma_f32_16x16x32_bf16(ah[m], bh[n], acc[m][n], 0, 0, 0);
          acc[m][n] = __builtin_amdgcn_mfma_f32_16x16x32_bf16(ah[m], bl[n], acc[m][n], 0, 0, 0);
          acc[m][n] = __builtin_amdgcn_mfma_f32_16x16x32_bf16(al[m], bh[n], acc[m][n], 0, 0, 0);
        }
      asm volatile("s_waitcnt lgkmcnt(0)" ::: "memory");
      __builtin_amdgcn_s_barrier();  // cur free for overwrite next iter
    }
    __syncthreads();

    // epilogue: 64-col halves through LDS, per-row top-3 scan
#pragma unroll
    for (int ph = 0; ph < 2; ++ph) {
      if (wc == ph) {
#pragma unroll
        for (int m = 0; m < 4; ++m)
#pragma unroll
          for (int n = 0; n < 4; ++n)
#pragma unroll
            for (int j = 0; j < 4; ++j)
              slog[(wr * 64 + m * 16 + kg * 4 + j) * LSTR + n * 16 + lr] = acc[m][n][j];
      }
      __syncthreads();
      if (tid < 128) {
        const int gbase = code0 + ph * 64;
        for (int c = 0; c < 64; ++c) {
          float v = slog[tid * LSTR + c];
          int gc = gbase + c;
          if (v > v1)      { v3 = v2; i3 = i2; v2 = v1; i2 = i1; v1 = v; i1 = gc; }
          else if (v > v2) { v3 = v2; i3 = i2; v2 = v;  i2 = gc; }
          else if (v > v3) { v3 = v;  i3 = gc; }
        }
      }
      __syncthreads();
    }
  }

  if (tid < 128) {
    float* p = top3 + ((size_t)(rb * 128 + tid) * GROUPS + cg) * 6;
    p[0] = v1; p[1] = v2; p[2] = v3;
    int* pi = (int*)p;
    pi[3] = i1; pi[4] = i2; pi[5] = i3;
  }
}

// ---------------- v1 GEMM (fallback when ws too small; known-correct) ----------------
__global__ __launch_bounds__(256, 2) void gemm_top3_kernel(
    const float* __restrict__ z, const float* __restrict__ cb,
    const float* __restrict__ inv_nz, const float* __restrict__ inv_nc,
    float* __restrict__ top3) {
  __shared__ unsigned short smem_u[20480];
  unsigned short* sAh = smem_u;
  unsigned short* sAl = smem_u + 5120;
  unsigned short* sBh = smem_u + 10240;
  unsigned short* sBl = smem_u + 15360;
  float* slog = (float*)smem_u;

  const int tid = threadIdx.x;
  const int rb = blockIdx.x >> 3;
  const int cg = blockIdx.x & 7;
  const int wave = tid >> 6, lane = tid & 63;
  const int wr = wave >> 1, wc = wave & 1;
  const int kg = lane >> 4, lr = lane & 15;
  const int srow = tid >> 3;
  const int scol = (tid & 7) << 2;

  float nza[4];
#pragma unroll
  for (int q = 0; q < 4; ++q) nza[q] = inv_nz[rb * 128 + q * 32 + srow];

  float v1 = -3e38f, v2 = -3e38f, v3 = -3e38f;
  int i1 = 0, i2 = 0, i3 = 0;

  for (int ct = 0; ct < 4; ++ct) {
    const int code0 = cg * 512 + ct * 128;
    float ncb[4];
#pragma unroll
    for (int q = 0; q < 4; ++q) ncb[q] = inv_nc[code0 + q * 32 + srow];

    f32x4_t acc[4][4];
#pragma unroll
    for (int m = 0; m < 4; ++m)
#pragma unroll
      for (int n = 0; n < 4; ++n) acc[m][n] = (f32x4_t){0.f, 0.f, 0.f, 0.f};

    f32x4_t ra[4], rbv[4];

    auto stage_load = [&](int t) {
      const int kc = t * 32 + scol;
#pragma unroll
      for (int q = 0; q < 4; ++q) {
        ra[q]  = *(const f32x4_t*)(z  + (size_t)(rb * 128 + q * 32 + srow) * DIM + kc);
        rbv[q] = *(const f32x4_t*)(cb + (size_t)(code0   + q * 32 + srow) * DIM + kc);
      }
    };
    auto stage_write = [&]() {
#pragma unroll
      for (int q = 0; q < 4; ++q) {
        const int row = q * 32 + srow;
        ushort4 hv, lv, hv2, lv2;
#pragma unroll
        for (int e = 0; e < 4; ++e) {
          float x = ra[q][e] * nza[q];
          unsigned short h = f2bf(x);
          (&hv.x)[e] = h;
          (&lv.x)[e] = f2bf(x - bf2f(h));
          float y = rbv[q][e] * ncb[q];
          unsigned short h2 = f2bf(y);
          (&hv2.x)[e] = h2;
          (&lv2.x)[e] = f2bf(y - bf2f(h2));
        }
        *(ushort4*)(sAh + row * SP + scol) = hv;
        *(ushort4*)(sAl + row * SP + scol) = lv;
        *(ushort4*)(sBh + row * SP + scol) = hv2;
        *(ushort4*)(sBl + row * SP + scol) = lv2;
      }
    };

    stage_load(0);
    stage_write();
    __syncthreads();

    for (int t = 0; t < 16; ++t) {
      if (t < 15) stage_load(t + 1);
      bf16x8_t ah[4], al[4], bh[4], bl[4];
#pragma unroll
      for (int m = 0; m < 4; ++m) {
        const int o = (wr * 64 + m * 16 + lr) * SP + kg * 8;
        ah[m] = *(const bf16x8_t*)(sAh + o);
        al[m] = *(const bf16x8_t*)(sAl + o);
      }
#pragma unroll
      for (int n = 0; n < 4; ++n) {
        const int o = (wc * 64 + n * 16 + lr) * SP + kg * 8;
        bh[n] = *(const bf16x8_t*)(sBh + o);
        bl[n] = *(const bf16x8_t*)(sBl + o);
      }
#pragma unroll
      for (int m = 0; m < 4; ++m)
#pragma unroll
        for (int n = 0; n < 4; ++n) {
          acc[m][n] = __builtin_amdgcn_mfma_f32_16x16x32_bf16(ah[m], bh[n], acc[m][n], 0, 0, 0);
          acc[m][n] = __builtin_amdgcn_mfma_f32_16x16x32_bf16(ah[m], bl[n], acc[m][n], 0, 0, 0);
          acc[m][n] = __builtin_amdgcn_mfma_f32_16x16x32_bf16(al[m], bh[n], acc[m][n], 0, 0, 0);
        }
      __syncthreads();
      if (t < 15) stage_write();
      __syncthreads();
    }

#pragma unroll
    for (int ph = 0; ph < 2; ++ph) {
      if (wc == ph) {
#pragma unroll
        for (int m = 0; m < 4; ++m)
#pragma unroll
          for (int n = 0; n < 4; ++n)
#pragma unroll
            for (int j = 0; j < 4; ++j)
              slog[(wr * 64 + m * 16 + kg * 4 + j) * LSTR + n * 16 + lr] = acc[m][n][j];
      }
      __syncthreads();
      if (tid < 128) {
        const int gbase = code0 + ph * 64;
        for (int c = 0; c < 64; ++c) {
          float v = slog[tid * LSTR + c];
          int gc = gbase + c;
          if (v > v1)      { v3 = v2; i3 = i2; v2 = v1; i2 = i1; v1 = v; i1 = gc; }
          else if (v > v2) { v3 = v2; i3 = i2; v2 = v;  i2 = gc; }
          else if (v > v3) { v3 = v;  i3 = gc; }
        }
      }
      __syncthreads();
    }
  }

  if (tid < 128) {
    float* p = top3 + ((size_t)(rb * 128 + tid) * GROUPS + cg) * 6;
    p[0] = v1; p[1] = v2; p[2] = v3;
    int* pi = (int*)p;
    pi[3] = i1; pi[4] = i2; pi[5] = i3;
  }
}

// ---------------- merge partial top-3, classify rows ----------------
__global__ void resolve_kernel(const float* __restrict__ top3, int* __restrict__ idxf,
                               int4* __restrict__ pairs, unsigned* __restrict__ pcnt,
                               int* __restrict__ full, unsigned* __restrict__ fcnt) {
  const int row = blockIdx.x * 256 + threadIdx.x;
  if (row >= NROWS) return;
  float V1 = -3e38f, V2 = -3e38f, V3 = -3e38f;
  int I1 = 0, I2 = 0, I3 = 0;
  const float* p = top3 + (size_t)row * GROUPS * 6;
  for (int g = 0; g < GROUPS; ++g, p += 6) {
    const int* pi = (const int*)p;
#pragma unroll
    for (int c = 0; c < 3; ++c) {
      float v = p[c]; int i = pi[3 + c];
      if (v > V1)      { V3 = V2; I3 = I2; V2 = V1; I2 = I1; V1 = v; I1 = i; }
      else if (v > V2) { V3 = V2; I3 = I2; V2 = v;  I2 = i; }
      else if (v > V3) { V3 = v;  I3 = i; }
    }
  }
  idxf[row] = I1;
  if (V1 - V2 <= MARGIN) {
    if (V1 - V3 <= MARGIN) {
      unsigned s = atomicAdd(fcnt, 1u);
      if (s < NROWS) full[s] = row;
    } else {
      unsigned s = atomicAdd(pcnt, 1u);
      if (s < NROWS) pairs[s] = make_int4(row, I1, I2, 0);
    }
  }
}

// ---------------- exact f64 rescore of {I1,I2} ----------------
__global__ void rescore_pairs_kernel(const float* __restrict__ z, const float* __restrict__ cb,
                                     const int4* __restrict__ pairs, const unsigned* __restrict__ pcnt,
                                     int* __restrict__ idxf) {
  const int lane = threadIdx.x & 63;
  const int gw = (blockIdx.x * 256 + threadIdx.x) >> 6;
  const unsigned n = *pcnt;
  for (unsigned it = gw; it < n; it += 512) {
    int4 e = pairs[it];
    const float* zr = z + (size_t)e.x * DIM;
    const float* ca = cb + (size_t)e.y * DIM;
    const float* cc = cb + (size_t)e.z * DIM;
    double da = 0, na = 0, db = 0, nb = 0;
#pragma unroll
    for (int j = 0; j < 8; ++j) {
      int o = lane * 8 + j;
      double zv = zr[o], av = ca[o], bv = cc[o];
      da += zv * av; na += av * av; db += zv * bv; nb += bv * bv;
    }
#pragma unroll
    for (int off = 32; off; off >>= 1) {
      da += __shfl_down(da, off); na += __shfl_down(na, off);
      db += __shfl_down(db, off); nb += __shfl_down(nb, off);
    }
    if (lane == 0) {
      double sa = da / sqrt(na), sb = db / sqrt(nb);
      int w = (sb > sa) ? e.z : ((sa > sb) ? e.y : (e.y < e.z ? e.y : e.z));
      idxf[e.x] = w;
    }
  }
}

// ---------------- exact f64 full-row scan (rare) ----------------
__global__ void rescore_full_kernel(const float* __restrict__ z, const float* __restrict__ cb,
                                    const int* __restrict__ full, const unsigned* __restrict__ fcnt,
                                    int* __restrict__ idxf) {
  __shared__ float zrow[DIM];
  __shared__ double rv[256];
  __shared__ int ri[256];
  const int t = threadIdx.x;
  const unsigned n = *fcnt;
  for (unsigned it = blockIdx.x; it < n; it += gridDim.x) {
    const int row = full[it];
    for (int j = t; j < DIM; j += 256) zrow[j] = z[(size_t)row * DIM + j];
    __syncthreads();
    double bv = -1e300; int bi = 1 << 30;
    for (int k = t; k < NCODES; k += 256) {
      const float* ck = cb + (size_t)k * DIM;
      double d = 0, nn = 0;
      for (int j = 0; j < DIM; ++j) { double c = ck[j]; d += (double)zrow[j] * c; nn += c * c; }
      double s = d / sqrt(nn);
      if (s > bv || (s == bv && k < bi)) { bv = s; bi = k; }
    }
    rv[t] = bv; ri[t] = bi; __syncthreads();
    for (int off = 128; off; off >>= 1) {
      if (t < off) {
        if (rv[t + off] > rv[t] || (rv[t + off] == rv[t] && ri[t + off] < ri[t])) {
          rv[t] = rv[t + off]; ri[t] = ri[t + off];
        }
      }
      __syncthreads();
    }
    if (t == 0) idxf[row] = ri[0];
    __syncthreads();
  }
}

// ---------------- gather + straight-through + partial losses ----------------
__global__ void outputs_kernel(const float* __restrict__ z, const float* __restrict__ cb,
                               const unsigned char* __restrict__ mask8, const int* __restrict__ mask32,
                               const unsigned* __restrict__ flags, const int* __restrict__ idxf,
                               float* __restrict__ out, unsigned* __restrict__ counts,
                               double* __restrict__ cpart) {
  __shared__ double wsum[4];
  const int wv = threadIdx.x >> 6, lane = threadIdx.x & 63;
  const int row = blockIdx.x * 4 + wv;
  int idx = idxf[row];
  idx = (idx < 0) ? 0 : ((idx > NCODES - 1) ? NCODES - 1 : idx);
  const int mi = flags[0] ? (mask32[row] != 0) : (mask8[row] != 0);
  const float mf = mi ? 1.0f : 0.0f;
  const float* zr = z + (size_t)row * DIM;
  const float* cr = cb + (size_t)idx * DIM;
  double cs = 0.0;
#pragma unroll
  for (int h = 0; h < 2; ++h) {
    const int j = h * 256 + lane * 4;
    f32x4_t c  = *(const f32x4_t*)(cr + j);
    f32x4_t ze = *(const f32x4_t*)(zr + j);
    f32x4_t zq, zs;
#pragma unroll
    for (int e = 0; e < 4; ++e) {
      float q = c[e] * mf;
      float d = q - ze[e];
      zq[e] = q;
      zs[e] = ze[e] + d;
      float d2 = d * d;
      cs += (double)d2 * mf;
    }
    *(f32x4_t*)(out + OUT_ZQ   + (size_t)row * DIM + j) = zq;
    *(f32x4_t*)(out + OUT_ZQST + (size_t)row * DIM + j) = zs;
  }
#pragma unroll
  for (int off = 32; off; off >>= 1) cs += __shfl_down(cs, off);
  if (lane == 0) {
    wsum[wv] = cs;
    out[OUT_IDX + row] = (float)idx;
    if (mi) atomicAdd(&counts[idx], 1u);
  }
  __syncthreads();
  if (threadIdx.x == 0) cpart[blockIdx.x] = wsum[0] + wsum[1] + wsum[2] + wsum[3];
}

// ---------------- scalars ----------------
__global__ void finalize_kernel(const double* __restrict__ cpart, const unsigned* __restrict__ counts,
                                float* __restrict__ out) {
  __shared__ double sd[256];
  const int t = threadIdx.x;
  double s = 0;
  for (int i = t; i < 4096; i += 256) s += cpart[i];
  sd[t] = s; __syncthreads();
  for (int off = 128; off; off >>= 1) { if (t < off) sd[t] += sd[t + off]; __syncthreads(); }
  const double commit_sum = sd[0];
  __syncthreads();
  double c = 0;
  for (int i = t; i < 4096; i += 256) c += (double)counts[i];
  sd[t] = c; __syncthreads();
  for (int off = 128; off; off >>= 1) { if (t < off) sd[t] += sd[t + off]; __syncthreads(); }
  const double totc = sd[0];
  __syncthreads();
  const double denom = totc + 1e-5;
  double ent = 0;
  for (int i = t; i < 4096; i += 256) {
    double p = (double)counts[i] / denom;
    ent -= p * log(p + 1e-5);
  }
  sd[t] = ent; __syncthreads();
  for (int off = 128; off; off >>= 1) { if (t < off) sd[t] += sd[t + off]; __syncthreads(); }
  if (t == 0) {
    const double valid = fmax(totc, 1.0);
    const double commitment = commit_sum / valid;
    out[OUT_VQ]     = (float)(0.25 * commitment);
    out[OUT_COMMIT] = (float)commitment;
    out[OUT_PERP]   = (float)exp(sd[0]);
  }
}

extern "C" void kernel_launch(void* const* d_in, const int* in_sizes, int n_in,
                              void* d_out, int out_size, void* d_ws, size_t ws_size,
                              hipStream_t stream) {
  const float* z  = (const float*)d_in[0];
  const void*  mk = d_in[1];
  const float* cb = (const float*)d_in[2];
  float* out = (float*)d_out;
  char* ws = (char*)d_ws;

  const bool v2 = (ws_size >= (size_t)WS2_TOTAL);

  float*    inv_nz = (float*)(ws + (v2 ? WS2_INV_NZ : WS_INV_NZ));
  float*    inv_nc = (float*)(ws + (v2 ? WS2_INV_NC : WS_INV_NC));
  unsigned* counts = (unsigned*)(ws + (v2 ? WS2_COUNTS : WS_COUNTS));
  unsigned* flags  = (unsigned*)(ws + (v2 ? WS2_FLAGS : WS_FLAGS));
  float*    top3   = (float*)(ws + (v2 ? WS2_TOP3 : WS_TOP3));
  int*      idxf   = (int*)(ws + (v2 ? WS2_IDX : WS_IDX));
  int4*     pairs  = (int4*)(ws + (v2 ? WS2_PAIRS : WS_PAIRS));
  int*      full   = (int*)(ws + (v2 ? WS2_FULL : WS_FULL));
  double*   cpart  = (double*)(ws + (v2 ? WS2_CPART : WS_CPART));

  hipMemsetAsync((void*)counts, 0, 16384 + 4096, stream);
  mask_probe_kernel<<<1, 256, 0, stream>>>((const uint4*)mk, flags);
  norms_kernel<<<(NROWS + NCODES) / 4, 256, 0, stream>>>(z, cb, inv_nz, inv_nc);
  if (v2) {
    unsigned char* Aws = (unsigned char*)(ws + WS2_A);
    unsigned char* Bws = (unsigned char*)(ws + WS2_B);
    prep_kernel<<<NROWS * 64 / 256, 256, 0, stream>>>(z, inv_nz, Aws, NROWS);
    prep_kernel<<<NCODES * 64 / 256, 256, 0, stream>>>(cb, inv_nc, Bws, NCODES);
    gemm_top3_v2_kernel<<<128 * GROUPS, 256, 0, stream>>>(Aws, Bws, top3);
  } else {
    gemm_top3_kernel<<<128 * GROUPS, 256, 0, stream>>>(z, cb, inv_nz, inv_nc, top3);
  }
  resolve_kernel<<<NROWS / 256, 256, 0, stream>>>(top3, idxf, pairs, flags + 1, full, flags + 2);
  rescore_pairs_kernel<<<128, 256, 0, stream>>>(z, cb, pairs, flags + 1, idxf);
  rescore_full_kernel<<<32, 256, 0, stream>>>(z, cb, full, flags + 2, idxf);
  outputs_kernel<<<NROWS / 4, 256, 0, stream>>>(z, cb, (const unsigned char*)mk, (const int*)mk,
                                                flags, idxf, out, counts, cpart);
  finalize_kernel<<<1, 256, 0, stream>>>(cpart, counts, out);
}